// Round 14
// baseline (398.906 us; speedup 1.0000x reference)
//
#include <hip/hip_runtime.h>
#include <math.h>

// Problem constants
#define N0 80000
#define N1 40000
#define N2 20000
#define E1C 500000
#define E2C 250000
#define NTYPE 23
#define NTS 1158

// derived grid constants
#define NB1 157
#define NB2 79
#define KV1B 1250
#define QR1B 625
#define CNTB 2930
#define KV2B 625
#define QR2B 313
#define FILLB 2930

// ---------------- Workspace layout (float offsets) ----------------
#define OFF_XB    0u
#define OFF_QR1   5120000u
#define OFF_KV1   15360000u
#define OFF_H     25600000u
#define OFF_QR2   28160000u
#define OFF_KV2   32000000u
#define OFF_WB1   37120000u
#define OFF_BP1   37160000u
#define OFF_WB2   37170000u
#define OFF_BP2   37200000u
#define OFF_TA1   37210000u
#define OFF_TB1   37213000u
#define OFF_TA2   37370000u
#define OFF_TB2   37373000u
#define OFF_RP1   37530000u
#define OFF_CUR1  37580000u
#define OFF_ED1   37630000u
#define OFF_BS1   38640000u
#define OFF_RP2   38650000u
#define OFF_CUR2  38680000u
#define OFF_ED2   38710000u
#define OFF_BS2   39220000u
#define OFF_DONE  39230000u

typedef __bf16 bf16x8 __attribute__((ext_vector_type(8)));
typedef float f32x4 __attribute__((ext_vector_type(4)));

static __device__ __forceinline__ float b2f(unsigned short u) {
    union { unsigned int i; float f; } c;
    c.i = ((unsigned int)u) << 16;
    return c.f;
}
static __device__ __forceinline__ unsigned short f2b(float f) {
    unsigned int u = __float_as_uint(f);
    unsigned int r = (u + 0x7fffu + ((u >> 16) & 1u)) >> 16;
    return (unsigned short)r;
}
static __device__ __forceinline__ bf16x8 ldfrag(const unsigned short* p) {
    return *reinterpret_cast<const bf16x8*>(p);
}

// DPP 16-lane reductions
template <int CTRL>
static __device__ __forceinline__ float dpp_addstep(float v) {
    int x = __builtin_amdgcn_mov_dpp(__float_as_int(v), CTRL, 0xF, 0xF, true);
    return v + __int_as_float(x);
}
static __device__ __forceinline__ float red16(float v) {
    v = dpp_addstep<0xB1>(v);
    v = dpp_addstep<0x4E>(v);
    v = dpp_addstep<0x141>(v);
    v = dpp_addstep<0x140>(v);
    return v;
}
template <int CTRL>
static __device__ __forceinline__ float dpp_maxstep(float v) {
    int x = __builtin_amdgcn_mov_dpp(__float_as_int(v), CTRL, 0xF, 0xF, true);
    return fmaxf(v, __int_as_float(x));
}
static __device__ __forceinline__ float red16max(float v) {
    v = dpp_maxstep<0xB1>(v);
    v = dpp_maxstep<0x4E>(v);
    v = dpp_maxstep<0x141>(v);
    v = dpp_maxstep<0x140>(v);
    return v;
}

// Edge-vector load + compute macros (3-buffer ring, no rotation movs)
#define EVLOAD(TAv, TBv, KUv, VUv, D)                                       \
    {                                                                       \
        int _sn = (int)(D).x, _t = (int)((D).y & 0xFFFF), _ts = (int)((D).y >> 16); \
        TAv = *(const float4*)(TA + _t * 128 + co);                         \
        TBv = *(const float4*)(TB + _ts * 128 + co);                        \
        const unsigned short* _kv = KV + (size_t)_sn * 256;                 \
        KUv = *(const ushort4*)(_kv + co);                                  \
        VUv = *(const ushort4*)(_kv + 128 + co);                            \
    }

#define EVCOMP(TAv, TBv, KUv, VUv)                                          \
    {                                                                       \
        float e0c = TAv.x + TBv.x, e1c = TAv.y + TBv.y;                     \
        float e2c = TAv.z + TBv.z, e3c = TAv.w + TBv.w;                     \
        float pp = q4.x * (b2f(KUv.x) + e0c) + q4.y * (b2f(KUv.y) + e1c)    \
                 + q4.z * (b2f(KUv.z) + e2c) + q4.w * (b2f(KUv.w) + e3c);   \
        pp = red16(pp);                                                     \
        float a = __expf(pp * 0.125f);                                      \
        ax += a * (b2f(VUv.x) + e0c); ay += a * (b2f(VUv.y) + e1c);         \
        az += a * (b2f(VUv.z) + e2c); aw += a * (b2f(VUv.w) + e3c);         \
        suma += a;                                                          \
    }

// ---------------------------------------------------------------------------
// Device GEMM bodies (MFMA 16x16x32 bf16), fragment-linear B.
// ---------------------------------------------------------------------------
#define LDSS 136

template <int NTILES>
static __device__ __forceinline__ void dev_gemm_bf16out(
    const unsigned short* __restrict__ XB, const unsigned short* __restrict__ WB,
    const float* __restrict__ BP, unsigned short* __restrict__ Y, int n, int blk,
    unsigned short* sb) {
    constexpr int COLS = NTILES * 16;
    constexpr int HALF = NTILES / 2;
    constexpr int HCOLS = HALF * 16;
    int wave = threadIdx.x >> 6, lane = threadIdx.x & 63;
    int m = lane & 15, quad = lane >> 4;
    int rowbase = blk * 64 + wave * 16;
    int arow = rowbase + m; if (arow >= n) arow = n - 1;
    unsigned short* swave = sb + wave * 16 * LDSS;
    const unsigned short* xrow = XB + (size_t)arow * 128 + quad * 8;
    bf16x8 a0 = ldfrag(xrow), a1 = ldfrag(xrow + 32);
    bf16x8 a2 = ldfrag(xrow + 64), a3 = ldfrag(xrow + 96);
    f32x4 acc[NTILES];
#pragma unroll
    for (int t = 0; t < NTILES; t++) acc[t] = (f32x4){0.f, 0.f, 0.f, 0.f};
#pragma unroll
    for (int t = 0; t < NTILES; t++) {
        const unsigned short* wt = WB + (size_t)t * 2048 + lane * 8;
        acc[t] = __builtin_amdgcn_mfma_f32_16x16x32_bf16(a0, ldfrag(wt), acc[t], 0, 0, 0);
        acc[t] = __builtin_amdgcn_mfma_f32_16x16x32_bf16(a1, ldfrag(wt + 512), acc[t], 0, 0, 0);
        acc[t] = __builtin_amdgcn_mfma_f32_16x16x32_bf16(a2, ldfrag(wt + 1024), acc[t], 0, 0, 0);
        acc[t] = __builtin_amdgcn_mfma_f32_16x16x32_bf16(a3, ldfrag(wt + 1536), acc[t], 0, 0, 0);
    }
    int tswz_bit = (quad >> 1) & 1;
#pragma unroll
    for (int half = 0; half < 2; half++) {
#pragma unroll
        for (int t = 0; t < HALF; t++) {
            int tt = half * HALF + t;
            int tsw = t ^ tswz_bit;
            float b = BP[tt * 16 + m];
#pragma unroll
            for (int r = 0; r < 4; r++)
                swave[(quad * 4 + r) * LDSS + tsw * 16 + m] = f2b(acc[tt][r] + b);
        }
#pragma unroll
        for (int i = 0; i < 4; i++) {
            int idx = i * 64 + lane;
            int r = idx / (HCOLS / 8), g = idx % (HCOLS / 8);
            int gs = g ^ (((r >> 3) & 1) << 1);
            int grow = rowbase + r;
            if (grow < n) {
                uint4 v = *(const uint4*)&swave[r * LDSS + gs * 8];
                *(uint4*)(Y + (size_t)grow * COLS + half * HCOLS + g * 8) = v;
            }
        }
    }
}

template <int NTILES>
static __device__ __forceinline__ void dev_gemm_f32out(
    const unsigned short* __restrict__ XB, const unsigned short* __restrict__ WB,
    const float* __restrict__ BP, float* __restrict__ Y, int n, int blk) {
    constexpr int COLS = NTILES * 16;
    int wave = threadIdx.x >> 6, lane = threadIdx.x & 63;
    int m = lane & 15, quad = lane >> 4;
    int rowbase = blk * 64 + wave * 16;
    int arow = rowbase + m; if (arow >= n) arow = n - 1;
    const unsigned short* xrow = XB + (size_t)arow * 128 + quad * 8;
    bf16x8 a0 = ldfrag(xrow), a1 = ldfrag(xrow + 32);
    bf16x8 a2 = ldfrag(xrow + 64), a3 = ldfrag(xrow + 96);
    f32x4 acc[NTILES];
#pragma unroll
    for (int t = 0; t < NTILES; t++) acc[t] = (f32x4){0.f, 0.f, 0.f, 0.f};
#pragma unroll
    for (int t = 0; t < NTILES; t++) {
        const unsigned short* wt = WB + (size_t)t * 2048 + lane * 8;
        acc[t] = __builtin_amdgcn_mfma_f32_16x16x32_bf16(a0, ldfrag(wt), acc[t], 0, 0, 0);
        acc[t] = __builtin_amdgcn_mfma_f32_16x16x32_bf16(a1, ldfrag(wt + 512), acc[t], 0, 0, 0);
        acc[t] = __builtin_amdgcn_mfma_f32_16x16x32_bf16(a2, ldfrag(wt + 1024), acc[t], 0, 0, 0);
        acc[t] = __builtin_amdgcn_mfma_f32_16x16x32_bf16(a3, ldfrag(wt + 1536), acc[t], 0, 0, 0);
    }
#pragma unroll
    for (int t = 0; t < NTILES; t++) {
        float b = BP[t * 16 + m];
#pragma unroll
        for (int r = 0; r < 4; r++) {
            int grow = rowbase + quad * 4 + r;
            if (grow < n) Y[(size_t)grow * COLS + t * 16 + m] = acc[t][r] + b;
        }
    }
}

// ---------------------------------------------------------------------------
// prep
// ---------------------------------------------------------------------------
__global__ __launch_bounds__(256) void prep(
    const float* __restrict__ x, unsigned short* __restrict__ XB,
    const float* __restrict__ Wk1, const float* __restrict__ Wv1,
    const float* __restrict__ Wq1, const float* __restrict__ Wskip1,
    const float* __restrict__ bk1, const float* __restrict__ bv1,
    const float* __restrict__ bq1, const float* __restrict__ bskip1,
    const float* __restrict__ Wk2, const float* __restrict__ Wv2,
    const float* __restrict__ Wq2, const float* __restrict__ Wskip2,
    const float* __restrict__ bk2, const float* __restrict__ bv2,
    const float* __restrict__ bq2, const float* __restrict__ bskip2,
    unsigned short* __restrict__ WB1, float* __restrict__ BP1,
    unsigned short* __restrict__ WB2, float* __restrict__ BP2,
    const float* __restrict__ edge_W, const float* __restrict__ edge_b,
    const float* __restrict__ time_W, const float* __restrict__ time_b,
    const float* __restrict__ We1, const float* __restrict__ We2,
    float* __restrict__ TA1, float* __restrict__ TB1,
    float* __restrict__ TA2, float* __restrict__ TB2,
    int* __restrict__ cnt1, int* __restrict__ cnt2, int* __restrict__ done) {
    int tid = blockIdx.x * blockDim.x + threadIdx.x;
    int stride = gridDim.x * blockDim.x;
    for (int i = tid; i < N0 * 32; i += stride) {
        float4 v = *(const float4*)(x + (size_t)i * 4);
        ushort4 u;
        u.x = f2b(v.x); u.y = f2b(v.y); u.z = f2b(v.z); u.w = f2b(v.w);
        *(ushort4*)(XB + (size_t)i * 4) = u;
    }
    for (int i = tid; i < 512 * 128; i += stride) {
        int j = i & 7, l = (i >> 3) & 63, ks = (i >> 9) & 3, t = i >> 11;
        int row = t * 16 + (l & 15);
        int col = ks * 32 + ((l >> 4) & 3) * 8 + j;
        const float* w; int off;
        if (row < 128) { w = Wk1; off = 0; }
        else if (row < 256) { w = Wv1; off = 128; }
        else if (row < 384) { w = Wq1; off = 256; }
        else { w = Wskip1; off = 384; }
        WB1[i] = f2b(w[(size_t)(row - off) * 128 + col]);
    }
    for (int i = tid; i < 512; i += stride) {
        const float* b; int off;
        if (i < 128) { b = bk1; off = 0; }
        else if (i < 256) { b = bv1; off = 128; }
        else if (i < 384) { b = bq1; off = 256; }
        else { b = bskip1; off = 384; }
        BP1[i] = b[i - off];
    }
    for (int i = tid; i < 448 * 128; i += stride) {
        int j = i & 7, l = (i >> 3) & 63, ks = (i >> 9) & 3, t = i >> 11;
        int row = t * 16 + (l & 15);
        int col = ks * 32 + ((l >> 4) & 3) * 8 + j;
        const float* w; int off;
        if (row < 128) { w = Wk2; off = 0; }
        else if (row < 256) { w = Wv2; off = 128; }
        else if (row < 384) { w = Wq2; off = 256; }
        else { w = Wskip2; off = 384; }
        WB2[i] = f2b(w[(size_t)(row - off) * 128 + col]);
    }
    for (int i = tid; i < 448; i += stride) {
        const float* b; int off;
        if (i < 128) { b = bk2; off = 0; }
        else if (i < 256) { b = bv2; off = 128; }
        else if (i < 384) { b = bq2; off = 256; }
        else { b = bskip2; off = 384; }
        BP2[i] = b[i - off];
    }
    const int TBL = (NTYPE + NTS) * 128;
    for (int i = tid; i < TBL; i += stride) {
        if (i < NTYPE * 128) {
            int e = i >> 7, c = i & 127;
            float s1 = 0.f, s2 = 0.f;
#pragma unroll
            for (int j = 0; j < 10; j++) {
                float fj = edge_W[j * NTYPE + e] + edge_b[j];
                s1 += fj * We1[c * 20 + j];
                s2 += fj * We2[c * 20 + j];
            }
            TA1[i] = s1; TA2[i] = s2;
        } else {
            int u = i - NTYPE * 128;
            int ts = u >> 7, c = u & 127;
            float s1 = 0.f, s2 = 0.f;
#pragma unroll
            for (int j = 0; j < 10; j++) {
                float fj = time_W[j * NTS + ts] + time_b[j];
                s1 += fj * We1[c * 20 + 10 + j];
                s2 += fj * We2[c * 20 + 10 + j];
            }
            TB1[u] = s1; TB2[u] = s2;
        }
    }
    for (int i = tid; i < N1 + N2 + 2; i += stride) {
        if (i < N1) cnt1[i] = 0;
        else if (i < N1 + N2) cnt2[i - N1] = 0;
        else done[i - N1 - N2] = 0;
    }
}

// ---------------------------------------------------------------------------
// mega_l1 / gemm_l2
// ---------------------------------------------------------------------------
__global__ __launch_bounds__(256) void mega_l1(
    const unsigned short* __restrict__ XB,
    const unsigned short* __restrict__ WB1, const float* __restrict__ BP1,
    unsigned short* __restrict__ KV1, float* __restrict__ QR1,
    const int* __restrict__ d1, const int* __restrict__ d2,
    int* __restrict__ cnt1, int* __restrict__ cnt2) {
    __shared__ unsigned short sbuf[4 * 16 * LDSS];
    int b = blockIdx.x;
    if (b < KV1B) {
        dev_gemm_bf16out<16>(XB, WB1, BP1, KV1, N0, b, sbuf);
    } else if (b < KV1B + QR1B) {
        dev_gemm_f32out<16>(XB, WB1 + 256 * 128, BP1 + 256, QR1, N1, b - KV1B);
    } else {
        int t = (b - KV1B - QR1B) * 256 + threadIdx.x;
        if (t < E1C) atomicAdd(&cnt1[d1[t]], 1);
        else {
            t -= E1C;
            if (t < E2C) atomicAdd(&cnt2[d2[t]], 1);
        }
    }
}

__global__ __launch_bounds__(256) void gemm_l2(
    const unsigned short* __restrict__ H,
    const unsigned short* __restrict__ WB2, const float* __restrict__ BP2,
    unsigned short* __restrict__ KV2, float* __restrict__ QR2) {
    __shared__ unsigned short sbuf[4 * 16 * LDSS];
    int b = blockIdx.x;
    if (b < KV2B) dev_gemm_bf16out<16>(H, WB2, BP2, KV2, N1, b, sbuf);
    else dev_gemm_f32out<12>(H, WB2 + 256 * 128, BP2 + 256, QR2, N2, b - KV2B);
}

// ---------------------------------------------------------------------------
// csr_scan
// ---------------------------------------------------------------------------
__global__ __launch_bounds__(256) void csr_scan(
    int* __restrict__ cnt1, int* __restrict__ bs1, int* __restrict__ rp1,
    int* __restrict__ cnt2, int* __restrict__ bs2, int* __restrict__ rp2,
    int* __restrict__ done) {
    __shared__ int s[256];
    __shared__ int amlast;
    int b = blockIdx.x;
    int* cnt; int* bs; int* rp; int n, lb;
    if (b < NB1) { cnt = cnt1; bs = bs1; rp = rp1; n = N1; lb = b; }
    else { cnt = cnt2; bs = bs2; rp = rp2; n = N2; lb = b - NB1; }
    int t = lb * 256 + threadIdx.x;
    int v = (t < n) ? cnt[t] : 0;
    s[threadIdx.x] = v;
    __syncthreads();
    for (int off = 128; off; off >>= 1) {
        if (threadIdx.x < off) s[threadIdx.x] += s[threadIdx.x + off];
        __syncthreads();
    }
    if (threadIdx.x == 0) {
        atomicExch(&bs[lb], s[0]);
        __threadfence();
        int prev = atomicAdd(&done[0], 1);
        amlast = (prev == NB1 + NB2 - 1) ? 1 : 0;
    }
    __syncthreads();
    if (amlast) {
        int tt = threadIdx.x;
        int v1 = (tt < NB1) ? atomicAdd(&bs1[tt], 0) : 0;
        s[tt] = v1;
        __syncthreads();
        for (int off = 1; off < 256; off <<= 1) {
            int u = (tt >= off) ? s[tt - off] : 0;
            __syncthreads();
            s[tt] += u;
            __syncthreads();
        }
        if (tt < NB1) atomicExch(&bs1[tt], s[tt] - v1);
        __syncthreads();
        int v2 = (tt < NB2) ? atomicAdd(&bs2[tt], 0) : 0;
        s[tt] = v2;
        __syncthreads();
        for (int off = 1; off < 256; off <<= 1) {
            int u = (tt >= off) ? s[tt - off] : 0;
            __syncthreads();
            s[tt] += u;
            __syncthreads();
        }
        if (tt < NB2) atomicExch(&bs2[tt], s[tt] - v2);
        __threadfence();
        __syncthreads();
        if (tt == 0) atomicExch(&done[1], 1);
    }
    if (threadIdx.x == 0) {
        while (atomicAdd(&done[1], 0) == 0) __builtin_amdgcn_s_sleep(1);
    }
    __syncthreads();
    __threadfence();
    int base = atomicAdd(&bs[lb], 0);
    s[threadIdx.x] = v;
    __syncthreads();
    for (int off = 1; off < 256; off <<= 1) {
        int u = (threadIdx.x >= off) ? s[threadIdx.x - off] : 0;
        __syncthreads();
        s[threadIdx.x] += u;
        __syncthreads();
    }
    int incl = s[threadIdx.x];
    if (t < n) { rp[t] = base + incl - v; cnt[t] = 0; }
    if (t == n - 1) rp[n] = base + incl;
}

// ---------------------------------------------------------------------------
// fill_both
// ---------------------------------------------------------------------------
__global__ __launch_bounds__(256) void fill_both(
    const int* __restrict__ d1, const int* __restrict__ s1,
    const int* __restrict__ et1, const int* __restrict__ ets1,
    const int* __restrict__ rp1, int* __restrict__ cur1, uint2* __restrict__ ed1,
    const int* __restrict__ d2, const int* __restrict__ s2,
    const int* __restrict__ et2, const int* __restrict__ ets2,
    const int* __restrict__ rp2, int* __restrict__ cur2, uint2* __restrict__ ed2) {
    int t = blockIdx.x * 256 + threadIdx.x;
    if (t < E1C) {
        int d = d1[t];
        int pos = rp1[d] + atomicAdd(&cur1[d], 1);
        ed1[pos] = make_uint2((unsigned)s1[t],
                              (unsigned)(et1[t] | (ets1[t] << 16)));
    } else {
        t -= E1C;
        if (t < E2C) {
            int d = d2[t];
            int pos = rp2[d] + atomicAdd(&cur2[d], 1);
            ed2[pos] = make_uint2((unsigned)s2[t],
                                  (unsigned)(et2[t] | (ets2[t] << 16)));
        }
    }
}

// ---------------------------------------------------------------------------
// Fused aggregation: 3-buffer ring pipeline (no rotation movs) + DPP.
// ---------------------------------------------------------------------------
__global__ __launch_bounds__(256) void agg_layer1(
    const int* __restrict__ rowptr, const uint2* __restrict__ ED,
    const float* __restrict__ TA, const float* __restrict__ TB,
    const float* __restrict__ QR, const unsigned short* __restrict__ KV,
    const float* __restrict__ Wbeta,
    const float* __restrict__ ln_g, const float* __restrict__ ln_b,
    unsigned short* __restrict__ hout, int n) {
    int wid = (blockIdx.x * blockDim.x + threadIdx.x) >> 6;
    int lane = threadIdx.x & 63;
    if (wid >= n) return;
    int s = lane >> 5, cg = lane & 15;
    int co = ((lane >> 4) & 1) * 64 + 4 * cg;
    int beg = rowptr[wid], end = rowptr[wid + 1];
    float4 q4 = *(const float4*)(QR + (size_t)wid * 256 + co);
    float ax = 0.f, ay = 0.f, az = 0.f, aw = 0.f, suma = 0.f;
    int p = beg + s;
    if (p < end) {
        uint2 dA = ED[p];
        bool m1 = p + 2 < end;
        uint2 dB = ED[m1 ? p + 2 : beg];
        bool m2 = p + 4 < end;
        uint2 dC = ED[m2 ? p + 4 : beg];
        float4 taA, tbA, taB, tbB, taC, tbC;
        ushort4 kuA, vuA, kuB, vuB, kuC, vuC;
        EVLOAD(taA, tbA, kuA, vuA, dA);
        EVLOAD(taB, tbB, kuB, vuB, dB);
        int pn = p + 6;
        for (;;) {
            // step A: compute bufA, load bufC vectors, fetch idx->dA
            bool m3 = pn < end;
            dA = ED[m3 ? pn : beg];
            EVLOAD(taC, tbC, kuC, vuC, dC);
            EVCOMP(taA, tbA, kuA, vuA);
            if (!m1) break;
            pn += 2;
            // step B: compute bufB, load bufA vectors, fetch idx->dB
            bool m4 = pn < end;
            dB = ED[m4 ? pn : beg];
            EVLOAD(taA, tbA, kuA, vuA, dA);
            EVCOMP(taB, tbB, kuB, vuB);
            if (!m2) break;
            pn += 2;
            // step C: compute bufC, load bufB vectors, fetch idx->dC
            bool m5 = pn < end;
            dC = ED[m5 ? pn : beg];
            EVLOAD(taB, tbB, kuB, vuB, dB);
            EVCOMP(taC, tbC, kuC, vuC);
            if (!m3) break;
            pn += 2;
            m1 = m4; m2 = m5;
        }
    }
    ax += __shfl_xor(ax, 32); ay += __shfl_xor(ay, 32);
    az += __shfl_xor(az, 32); aw += __shfl_xor(aw, 32);
    suma += __shfl_xor(suma, 32);
    float inv_s = 1.f / (suma + 1e-16f);
    float ox = ax * inv_s, oy = ay * inv_s, oz = az * inv_s, ow = aw * inv_s;
    float4 r4 = *(const float4*)(QR + (size_t)wid * 256 + 128 + co);
    float4 wo = *(const float4*)(Wbeta + co);
    float4 wr = *(const float4*)(Wbeta + 128 + co);
    float4 wd = *(const float4*)(Wbeta + 256 + co);
    float pb = wo.x * ox + wr.x * r4.x + wd.x * (ox - r4.x)
             + wo.y * oy + wr.y * r4.y + wd.y * (oy - r4.y)
             + wo.z * oz + wr.z * r4.z + wd.z * (oz - r4.z)
             + wo.w * ow + wr.w * r4.w + wd.w * (ow - r4.w);
    pb = red16(pb);
    pb += __shfl_xor(pb, 16);
    float beta = 1.f / (1.f + __expf(-pb));
    float gx = beta * r4.x + (1.f - beta) * ox;
    float gy = beta * r4.y + (1.f - beta) * oy;
    float gz = beta * r4.z + (1.f - beta) * oz;
    float gw = beta * r4.w + (1.f - beta) * ow;
    float sm = gx + gy + gz + gw;
    float sq = gx * gx + gy * gy + gz * gz + gw * gw;
    sm = red16(sm); sm += __shfl_xor(sm, 16);
    sq = red16(sq); sq += __shfl_xor(sq, 16);
    float mu = sm * (1.f / 128.f);
    float var = sq * (1.f / 128.f) - mu * mu;
    float inv = rsqrtf(var + 1e-5f);
    float4 lg = *(const float4*)(ln_g + co);
    float4 lb = *(const float4*)(ln_b + co);
    float yx = (gx - mu) * inv * lg.x + lb.x;
    float yy = (gy - mu) * inv * lg.y + lb.y;
    float yz = (gz - mu) * inv * lg.z + lb.z;
    float yw = (gw - mu) * inv * lg.w + lb.w;
    const float ISQ2 = 0.70710678118654752f;
    yx = 0.5f * yx * (1.f + erff(yx * ISQ2));
    yy = 0.5f * yy * (1.f + erff(yy * ISQ2));
    yz = 0.5f * yz * (1.f + erff(yz * ISQ2));
    yw = 0.5f * yw * (1.f + erff(yw * ISQ2));
    if (s == 0) {
        ushort4 hv;
        hv.x = f2b(yx); hv.y = f2b(yy); hv.z = f2b(yz); hv.w = f2b(yw);
        *(ushort4*)(hout + (size_t)wid * 128 + co) = hv;
    }
}

__global__ __launch_bounds__(256) void agg_layer2(
    const int* __restrict__ rowptr, const uint2* __restrict__ ED,
    const float* __restrict__ TA, const float* __restrict__ TB,
    const float* __restrict__ QR, const unsigned short* __restrict__ KV,
    const float* __restrict__ Wbeta,
    float* __restrict__ o, int n) {
    int wid = (blockIdx.x * blockDim.x + threadIdx.x) >> 6;
    int lane = threadIdx.x & 63;
    if (wid >= n) return;
    int s = lane >> 5, cg = lane & 15;
    int co = ((lane >> 4) & 1) * 64 + 4 * cg;
    int beg = rowptr[wid], end = rowptr[wid + 1];
    float4 q4 = *(const float4*)(QR + (size_t)wid * 192 + co);
    float ax = 0.f, ay = 0.f, az = 0.f, aw = 0.f, suma = 0.f;
    int p = beg + s;
    if (p < end) {
        uint2 dA = ED[p];
        bool m1 = p + 2 < end;
        uint2 dB = ED[m1 ? p + 2 : beg];
        bool m2 = p + 4 < end;
        uint2 dC = ED[m2 ? p + 4 : beg];
        float4 taA, tbA, taB, tbB, taC, tbC;
        ushort4 kuA, vuA, kuB, vuB, kuC, vuC;
        EVLOAD(taA, tbA, kuA, vuA, dA);
        EVLOAD(taB, tbB, kuB, vuB, dB);
        int pn = p + 6;
        for (;;) {
            bool m3 = pn < end;
            dA = ED[m3 ? pn : beg];
            EVLOAD(taC, tbC, kuC, vuC, dC);
            EVCOMP(taA, tbA, kuA, vuA);
            if (!m1) break;
            pn += 2;
            bool m4 = pn < end;
            dB = ED[m4 ? pn : beg];
            EVLOAD(taA, tbA, kuA, vuA, dA);
            EVCOMP(taB, tbB, kuB, vuB);
            if (!m2) break;
            pn += 2;
            bool m5 = pn < end;
            dC = ED[m5 ? pn : beg];
            EVLOAD(taB, tbB, kuB, vuB, dB);
            EVCOMP(taC, tbC, kuC, vuC);
            if (!m3) break;
            pn += 2;
            m1 = m4; m2 = m5;
        }
    }
    ax += __shfl_xor(ax, 32); ay += __shfl_xor(ay, 32);
    az += __shfl_xor(az, 32); aw += __shfl_xor(aw, 32);
    suma += __shfl_xor(suma, 32);
    float inv_s = 1.f / (suma + 1e-16f);
    float ox = ax * inv_s, oy = ay * inv_s, oz = az * inv_s, ow = aw * inv_s;
    ox = 0.5f * (ox + __shfl_xor(ox, 16));
    oy = 0.5f * (oy + __shfl_xor(oy, 16));
    oz = 0.5f * (oz + __shfl_xor(oz, 16));
    ow = 0.5f * (ow + __shfl_xor(ow, 16));
    float4 r4 = *(const float4*)(QR + (size_t)wid * 192 + 128 + 4 * cg);
    float4 wo = *(const float4*)(Wbeta + 4 * cg);
    float4 wr = *(const float4*)(Wbeta + 64 + 4 * cg);
    float4 wd = *(const float4*)(Wbeta + 128 + 4 * cg);
    float pb = wo.x * ox + wr.x * r4.x + wd.x * (ox - r4.x)
             + wo.y * oy + wr.y * r4.y + wd.y * (oy - r4.y)
             + wo.z * oz + wr.z * r4.z + wd.z * (oz - r4.z)
             + wo.w * ow + wr.w * r4.w + wd.w * (ow - r4.w);
    pb = red16(pb);
    float beta = 1.f / (1.f + __expf(-pb));
    float vx = beta * r4.x + (1.f - beta) * ox;
    float vy = beta * r4.y + (1.f - beta) * oy;
    float vz = beta * r4.z + (1.f - beta) * oz;
    float vw = beta * r4.w + (1.f - beta) * ow;
    float m = fmaxf(fmaxf(vx, vy), fmaxf(vz, vw));
    m = red16max(m);
    float se = __expf(vx - m) + __expf(vy - m) + __expf(vz - m) + __expf(vw - m);
    se = red16(se);
    float lse = m + logf(se);
    if (lane < 16)
        *(float4*)(o + (size_t)wid * 64 + 4 * cg) =
            make_float4(vx - lse, vy - lse, vz - lse, vw - lse);
}

extern "C" void kernel_launch(void* const* d_in, const int* in_sizes, int n_in,
                              void* d_out, int out_size, void* d_ws, size_t ws_size,
                              hipStream_t stream) {
    const float* x        = (const float*)d_in[0];
    const int*   ei1_src  = (const int*)d_in[1];
    const int*   ei1_dst  = (const int*)d_in[2];
    const int*   et1      = (const int*)d_in[3];
    const int*   ets1     = (const int*)d_in[4];
    const int*   ei2_src  = (const int*)d_in[5];
    const int*   ei2_dst  = (const int*)d_in[6];
    const int*   et2      = (const int*)d_in[7];
    const int*   ets2     = (const int*)d_in[8];
    const float* edge_W   = (const float*)d_in[9];
    const float* edge_b   = (const float*)d_in[10];
    const float* time_W   = (const float*)d_in[11];
    const float* time_b   = (const float*)d_in[12];
    const float* Wq1      = (const float*)d_in[13];
    const float* bq1      = (const float*)d_in[14];
    const float* Wk1      = (const float*)d_in[15];
    const float* bk1      = (const float*)d_in[16];
    const float* Wv1      = (const float*)d_in[17];
    const float* bv1      = (const float*)d_in[18];
    const float* We1      = (const float*)d_in[19];
    const float* Wskip1   = (const float*)d_in[20];
    const float* bskip1   = (const float*)d_in[21];
    const float* Wbeta1   = (const float*)d_in[22];
    const float* ln_g     = (const float*)d_in[23];
    const float* ln_b     = (const float*)d_in[24];
    const float* Wq2      = (const float*)d_in[25];
    const float* bq2      = (const float*)d_in[26];
    const float* Wk2      = (const float*)d_in[27];
    const float* bk2      = (const float*)d_in[28];
    const float* Wv2      = (const float*)d_in[29];
    const float* bv2      = (const float*)d_in[30];
    const float* We2      = (const float*)d_in[31];
    const float* Wskip2   = (const float*)d_in[32];
    const float* bskip2   = (const float*)d_in[33];
    const float* Wbeta2   = (const float*)d_in[34];

    float* ws = (float*)d_ws;
    unsigned short* xb  = (unsigned short*)(ws + OFF_XB);
    float* qr1          = ws + OFF_QR1;
    unsigned short* kv1 = (unsigned short*)(ws + OFF_KV1);
    unsigned short* h   = (unsigned short*)(ws + OFF_H);
    float* qr2          = ws + OFF_QR2;
    unsigned short* kv2 = (unsigned short*)(ws + OFF_KV2);
    unsigned short* wb1 = (unsigned short*)(ws + OFF_WB1);
    float* bp1          = ws + OFF_BP1;
    unsigned short* wb2 = (unsigned short*)(ws + OFF_WB2);
    float* bp2          = ws + OFF_BP2;
    float* ta1          = ws + OFF_TA1;
    float* tb1          = ws + OFF_TB1;
    float* ta2          = ws + OFF_TA2;
    float* tb2          = ws + OFF_TB2;
    int*   rp1          = (int*)(ws + OFF_RP1);
    int*   cur1         = (int*)(ws + OFF_CUR1);
    uint2* ed1          = (uint2*)(ws + OFF_ED1);
    int*   bs1          = (int*)(ws + OFF_BS1);
    int*   rp2          = (int*)(ws + OFF_RP2);
    int*   cur2         = (int*)(ws + OFF_CUR2);
    uint2* ed2          = (uint2*)(ws + OFF_ED2);
    int*   bs2          = (int*)(ws + OFF_BS2);
    int*   done         = (int*)(ws + OFF_DONE);

    prep<<<2048, 256, 0, stream>>>(
        x, xb,
        Wk1, Wv1, Wq1, Wskip1, bk1, bv1, bq1, bskip1,
        Wk2, Wv2, Wq2, Wskip2, bk2, bv2, bq2, bskip2,
        wb1, bp1, wb2, bp2,
        edge_W, edge_b, time_W, time_b, We1, We2,
        ta1, tb1, ta2, tb2, cur1, cur2, done);
    mega_l1<<<KV1B + QR1B + CNTB, 256, 0, stream>>>(
        xb, wb1, bp1, kv1, qr1, ei1_dst, ei2_dst, cur1, cur2);
    csr_scan<<<NB1 + NB2, 256, 0, stream>>>(cur1, bs1, rp1, cur2, bs2, rp2, done);
    fill_both<<<FILLB, 256, 0, stream>>>(
        ei1_dst, ei1_src, et1, ets1, rp1, cur1, ed1,
        ei2_dst, ei2_src, et2, ets2, rp2, cur2, ed2);
    agg_layer1<<<(N1 + 3) / 4, 256, 0, stream>>>(rp1, ed1,
        ta1, tb1, qr1, kv1, Wbeta1, ln_g, ln_b, h, N1);
    gemm_l2<<<KV2B + QR2B, 256, 0, stream>>>(h, wb2, bp2, kv2, qr2);
    agg_layer2<<<(N2 + 3) / 4, 256, 0, stream>>>(rp2, ed2,
        ta2, tb2, qr2, kv2, Wbeta2, (float*)d_out, N2);
}

// Round 15
// 369.401 us; speedup vs baseline: 1.0799x; 1.0799x over previous
//
#include <hip/hip_runtime.h>
#include <math.h>

// Problem constants
#define N0 80000
#define N1 40000
#define N2 20000
#define E1C 500000
#define E2C 250000
#define NTYPE 23
#define NTS 1158

// derived grid constants
#define NB1 157
#define NB2 79
#define KV1B 1250
#define QR1B 625
#define CNTB 2930
#define KV2B 625
#define QR2B 313
#define FILLB 2930

// ---------------- Workspace layout (float offsets) ----------------
#define OFF_XB    0u
#define OFF_QR1   5120000u
#define OFF_KV1   15360000u
#define OFF_H     25600000u
#define OFF_QR2   28160000u
#define OFF_KV2   32000000u
#define OFF_WB1   37120000u
#define OFF_BP1   37160000u
#define OFF_WB2   37170000u
#define OFF_BP2   37200000u
#define OFF_TA1   37210000u
#define OFF_TB1   37213000u
#define OFF_TA2   37370000u
#define OFF_TB2   37373000u
#define OFF_RP1   37530000u
#define OFF_CUR1  37580000u
#define OFF_ED1   37630000u
#define OFF_BS1   38640000u
#define OFF_RP2   38650000u
#define OFF_CUR2  38680000u
#define OFF_ED2   38710000u
#define OFF_BS2   39220000u
#define OFF_DONE  39230000u    // 2 ints
#define OFF_RK1   39240000u    // E1 ints (edge rank within dst)
#define OFF_RK2   39740000u    // E2 ints -> ends 39,990,000 (~160 MB)

typedef __bf16 bf16x8 __attribute__((ext_vector_type(8)));
typedef float f32x4 __attribute__((ext_vector_type(4)));

static __device__ __forceinline__ float b2f(unsigned short u) {
    union { unsigned int i; float f; } c;
    c.i = ((unsigned int)u) << 16;
    return c.f;
}
static __device__ __forceinline__ unsigned short f2b(float f) {
    unsigned int u = __float_as_uint(f);
    unsigned int r = (u + 0x7fffu + ((u >> 16) & 1u)) >> 16;
    return (unsigned short)r;
}
static __device__ __forceinline__ bf16x8 ldfrag(const unsigned short* p) {
    return *reinterpret_cast<const bf16x8*>(p);
}

// DPP 16-lane reductions
template <int CTRL>
static __device__ __forceinline__ float dpp_addstep(float v) {
    int x = __builtin_amdgcn_mov_dpp(__float_as_int(v), CTRL, 0xF, 0xF, true);
    return v + __int_as_float(x);
}
static __device__ __forceinline__ float red16(float v) {
    v = dpp_addstep<0xB1>(v);
    v = dpp_addstep<0x4E>(v);
    v = dpp_addstep<0x141>(v);
    v = dpp_addstep<0x140>(v);
    return v;
}
template <int CTRL>
static __device__ __forceinline__ float dpp_maxstep(float v) {
    int x = __builtin_amdgcn_mov_dpp(__float_as_int(v), CTRL, 0xF, 0xF, true);
    return fmaxf(v, __int_as_float(x));
}
static __device__ __forceinline__ float red16max(float v) {
    v = dpp_maxstep<0xB1>(v);
    v = dpp_maxstep<0x4E>(v);
    v = dpp_maxstep<0x141>(v);
    v = dpp_maxstep<0x140>(v);
    return v;
}

// ---------------------------------------------------------------------------
// Device GEMM bodies (MFMA 16x16x32 bf16), fragment-linear B.
// ---------------------------------------------------------------------------
#define LDSS 136

template <int NTILES>
static __device__ __forceinline__ void dev_gemm_bf16out(
    const unsigned short* __restrict__ XB, const unsigned short* __restrict__ WB,
    const float* __restrict__ BP, unsigned short* __restrict__ Y, int n, int blk,
    unsigned short* sb) {
    constexpr int COLS = NTILES * 16;
    constexpr int HALF = NTILES / 2;
    constexpr int HCOLS = HALF * 16;
    int wave = threadIdx.x >> 6, lane = threadIdx.x & 63;
    int m = lane & 15, quad = lane >> 4;
    int rowbase = blk * 64 + wave * 16;
    int arow = rowbase + m; if (arow >= n) arow = n - 1;
    unsigned short* swave = sb + wave * 16 * LDSS;
    const unsigned short* xrow = XB + (size_t)arow * 128 + quad * 8;
    bf16x8 a0 = ldfrag(xrow), a1 = ldfrag(xrow + 32);
    bf16x8 a2 = ldfrag(xrow + 64), a3 = ldfrag(xrow + 96);
    f32x4 acc[NTILES];
#pragma unroll
    for (int t = 0; t < NTILES; t++) acc[t] = (f32x4){0.f, 0.f, 0.f, 0.f};
#pragma unroll
    for (int t = 0; t < NTILES; t++) {
        const unsigned short* wt = WB + (size_t)t * 2048 + lane * 8;
        acc[t] = __builtin_amdgcn_mfma_f32_16x16x32_bf16(a0, ldfrag(wt), acc[t], 0, 0, 0);
        acc[t] = __builtin_amdgcn_mfma_f32_16x16x32_bf16(a1, ldfrag(wt + 512), acc[t], 0, 0, 0);
        acc[t] = __builtin_amdgcn_mfma_f32_16x16x32_bf16(a2, ldfrag(wt + 1024), acc[t], 0, 0, 0);
        acc[t] = __builtin_amdgcn_mfma_f32_16x16x32_bf16(a3, ldfrag(wt + 1536), acc[t], 0, 0, 0);
    }
    int tswz_bit = (quad >> 1) & 1;
#pragma unroll
    for (int half = 0; half < 2; half++) {
#pragma unroll
        for (int t = 0; t < HALF; t++) {
            int tt = half * HALF + t;
            int tsw = t ^ tswz_bit;
            float b = BP[tt * 16 + m];
#pragma unroll
            for (int r = 0; r < 4; r++)
                swave[(quad * 4 + r) * LDSS + tsw * 16 + m] = f2b(acc[tt][r] + b);
        }
#pragma unroll
        for (int i = 0; i < 4; i++) {
            int idx = i * 64 + lane;
            int r = idx / (HCOLS / 8), g = idx % (HCOLS / 8);
            int gs = g ^ (((r >> 3) & 1) << 1);
            int grow = rowbase + r;
            if (grow < n) {
                uint4 v = *(const uint4*)&swave[r * LDSS + gs * 8];
                *(uint4*)(Y + (size_t)grow * COLS + half * HCOLS + g * 8) = v;
            }
        }
    }
}

template <int NTILES>
static __device__ __forceinline__ void dev_gemm_f32out(
    const unsigned short* __restrict__ XB, const unsigned short* __restrict__ WB,
    const float* __restrict__ BP, float* __restrict__ Y, int n, int blk) {
    constexpr int COLS = NTILES * 16;
    int wave = threadIdx.x >> 6, lane = threadIdx.x & 63;
    int m = lane & 15, quad = lane >> 4;
    int rowbase = blk * 64 + wave * 16;
    int arow = rowbase + m; if (arow >= n) arow = n - 1;
    const unsigned short* xrow = XB + (size_t)arow * 128 + quad * 8;
    bf16x8 a0 = ldfrag(xrow), a1 = ldfrag(xrow + 32);
    bf16x8 a2 = ldfrag(xrow + 64), a3 = ldfrag(xrow + 96);
    f32x4 acc[NTILES];
#pragma unroll
    for (int t = 0; t < NTILES; t++) acc[t] = (f32x4){0.f, 0.f, 0.f, 0.f};
#pragma unroll
    for (int t = 0; t < NTILES; t++) {
        const unsigned short* wt = WB + (size_t)t * 2048 + lane * 8;
        acc[t] = __builtin_amdgcn_mfma_f32_16x16x32_bf16(a0, ldfrag(wt), acc[t], 0, 0, 0);
        acc[t] = __builtin_amdgcn_mfma_f32_16x16x32_bf16(a1, ldfrag(wt + 512), acc[t], 0, 0, 0);
        acc[t] = __builtin_amdgcn_mfma_f32_16x16x32_bf16(a2, ldfrag(wt + 1024), acc[t], 0, 0, 0);
        acc[t] = __builtin_amdgcn_mfma_f32_16x16x32_bf16(a3, ldfrag(wt + 1536), acc[t], 0, 0, 0);
    }
#pragma unroll
    for (int t = 0; t < NTILES; t++) {
        float b = BP[t * 16 + m];
#pragma unroll
        for (int r = 0; r < 4; r++) {
            int grow = rowbase + quad * 4 + r;
            if (grow < n) Y[(size_t)grow * COLS + t * 16 + m] = acc[t][r] + b;
        }
    }
}

// ---------------------------------------------------------------------------
// prep
// ---------------------------------------------------------------------------
__global__ __launch_bounds__(256) void prep(
    const float* __restrict__ x, unsigned short* __restrict__ XB,
    const float* __restrict__ Wk1, const float* __restrict__ Wv1,
    const float* __restrict__ Wq1, const float* __restrict__ Wskip1,
    const float* __restrict__ bk1, const float* __restrict__ bv1,
    const float* __restrict__ bq1, const float* __restrict__ bskip1,
    const float* __restrict__ Wk2, const float* __restrict__ Wv2,
    const float* __restrict__ Wq2, const float* __restrict__ Wskip2,
    const float* __restrict__ bk2, const float* __restrict__ bv2,
    const float* __restrict__ bq2, const float* __restrict__ bskip2,
    unsigned short* __restrict__ WB1, float* __restrict__ BP1,
    unsigned short* __restrict__ WB2, float* __restrict__ BP2,
    const float* __restrict__ edge_W, const float* __restrict__ edge_b,
    const float* __restrict__ time_W, const float* __restrict__ time_b,
    const float* __restrict__ We1, const float* __restrict__ We2,
    float* __restrict__ TA1, float* __restrict__ TB1,
    float* __restrict__ TA2, float* __restrict__ TB2,
    int* __restrict__ cnt1, int* __restrict__ cnt2, int* __restrict__ done) {
    int tid = blockIdx.x * blockDim.x + threadIdx.x;
    int stride = gridDim.x * blockDim.x;
    for (int i = tid; i < N0 * 32; i += stride) {
        float4 v = *(const float4*)(x + (size_t)i * 4);
        ushort4 u;
        u.x = f2b(v.x); u.y = f2b(v.y); u.z = f2b(v.z); u.w = f2b(v.w);
        *(ushort4*)(XB + (size_t)i * 4) = u;
    }
    for (int i = tid; i < 512 * 128; i += stride) {
        int j = i & 7, l = (i >> 3) & 63, ks = (i >> 9) & 3, t = i >> 11;
        int row = t * 16 + (l & 15);
        int col = ks * 32 + ((l >> 4) & 3) * 8 + j;
        const float* w; int off;
        if (row < 128) { w = Wk1; off = 0; }
        else if (row < 256) { w = Wv1; off = 128; }
        else if (row < 384) { w = Wq1; off = 256; }
        else { w = Wskip1; off = 384; }
        WB1[i] = f2b(w[(size_t)(row - off) * 128 + col]);
    }
    for (int i = tid; i < 512; i += stride) {
        const float* b; int off;
        if (i < 128) { b = bk1; off = 0; }
        else if (i < 256) { b = bv1; off = 128; }
        else if (i < 384) { b = bq1; off = 256; }
        else { b = bskip1; off = 384; }
        BP1[i] = b[i - off];
    }
    for (int i = tid; i < 448 * 128; i += stride) {
        int j = i & 7, l = (i >> 3) & 63, ks = (i >> 9) & 3, t = i >> 11;
        int row = t * 16 + (l & 15);
        int col = ks * 32 + ((l >> 4) & 3) * 8 + j;
        const float* w; int off;
        if (row < 128) { w = Wk2; off = 0; }
        else if (row < 256) { w = Wv2; off = 128; }
        else if (row < 384) { w = Wq2; off = 256; }
        else { w = Wskip2; off = 384; }
        WB2[i] = f2b(w[(size_t)(row - off) * 128 + col]);
    }
    for (int i = tid; i < 448; i += stride) {
        const float* b; int off;
        if (i < 128) { b = bk2; off = 0; }
        else if (i < 256) { b = bv2; off = 128; }
        else if (i < 384) { b = bq2; off = 256; }
        else { b = bskip2; off = 384; }
        BP2[i] = b[i - off];
    }
    const int TBL = (NTYPE + NTS) * 128;
    for (int i = tid; i < TBL; i += stride) {
        if (i < NTYPE * 128) {
            int e = i >> 7, c = i & 127;
            float s1 = 0.f, s2 = 0.f;
#pragma unroll
            for (int j = 0; j < 10; j++) {
                float fj = edge_W[j * NTYPE + e] + edge_b[j];
                s1 += fj * We1[c * 20 + j];
                s2 += fj * We2[c * 20 + j];
            }
            TA1[i] = s1; TA2[i] = s2;
        } else {
            int u = i - NTYPE * 128;
            int ts = u >> 7, c = u & 127;
            float s1 = 0.f, s2 = 0.f;
#pragma unroll
            for (int j = 0; j < 10; j++) {
                float fj = time_W[j * NTS + ts] + time_b[j];
                s1 += fj * We1[c * 20 + 10 + j];
                s2 += fj * We2[c * 20 + 10 + j];
            }
            TB1[u] = s1; TB2[u] = s2;
        }
    }
    for (int i = tid; i < N1 + N2 + 2; i += stride) {
        if (i < N1) cnt1[i] = 0;
        else if (i < N1 + N2) cnt2[i - N1] = 0;
        else done[i - N1 - N2] = 0;
    }
}

// ---------------------------------------------------------------------------
// mega_l1: KV1 GEMM | QR1 GEMM | degree count (stores per-edge rank)
// ---------------------------------------------------------------------------
__global__ __launch_bounds__(256) void mega_l1(
    const unsigned short* __restrict__ XB,
    const unsigned short* __restrict__ WB1, const float* __restrict__ BP1,
    unsigned short* __restrict__ KV1, float* __restrict__ QR1,
    const int* __restrict__ d1, const int* __restrict__ d2,
    int* __restrict__ cnt1, int* __restrict__ cnt2,
    int* __restrict__ rk1, int* __restrict__ rk2) {
    __shared__ unsigned short sbuf[4 * 16 * LDSS];
    int b = blockIdx.x;
    if (b < KV1B) {
        dev_gemm_bf16out<16>(XB, WB1, BP1, KV1, N0, b, sbuf);
    } else if (b < KV1B + QR1B) {
        dev_gemm_f32out<16>(XB, WB1 + 256 * 128, BP1 + 256, QR1, N1, b - KV1B);
    } else {
        int t = (b - KV1B - QR1B) * 256 + threadIdx.x;
        if (t < E1C) rk1[t] = atomicAdd(&cnt1[d1[t]], 1);
        else {
            t -= E1C;
            if (t < E2C) rk2[t] = atomicAdd(&cnt2[d2[t]], 1);
        }
    }
}

__global__ __launch_bounds__(256) void gemm_l2(
    const unsigned short* __restrict__ H,
    const unsigned short* __restrict__ WB2, const float* __restrict__ BP2,
    unsigned short* __restrict__ KV2, float* __restrict__ QR2) {
    __shared__ unsigned short sbuf[4 * 16 * LDSS];
    int b = blockIdx.x;
    if (b < KV2B) dev_gemm_bf16out<16>(H, WB2, BP2, KV2, N1, b, sbuf);
    else dev_gemm_f32out<12>(H, WB2 + 256 * 128, BP2 + 256, QR2, N2, b - KV2B);
}

// ---------------------------------------------------------------------------
// csr_scan (no cursor re-zero needed — fill uses precomputed ranks)
// ---------------------------------------------------------------------------
__global__ __launch_bounds__(256) void csr_scan(
    int* __restrict__ cnt1, int* __restrict__ bs1, int* __restrict__ rp1,
    int* __restrict__ cnt2, int* __restrict__ bs2, int* __restrict__ rp2,
    int* __restrict__ done) {
    __shared__ int s[256];
    __shared__ int amlast;
    int b = blockIdx.x;
    int* cnt; int* bs; int* rp; int n, lb;
    if (b < NB1) { cnt = cnt1; bs = bs1; rp = rp1; n = N1; lb = b; }
    else { cnt = cnt2; bs = bs2; rp = rp2; n = N2; lb = b - NB1; }
    int t = lb * 256 + threadIdx.x;
    int v = (t < n) ? cnt[t] : 0;
    s[threadIdx.x] = v;
    __syncthreads();
    for (int off = 128; off; off >>= 1) {
        if (threadIdx.x < off) s[threadIdx.x] += s[threadIdx.x + off];
        __syncthreads();
    }
    if (threadIdx.x == 0) {
        atomicExch(&bs[lb], s[0]);
        __threadfence();
        int prev = atomicAdd(&done[0], 1);
        amlast = (prev == NB1 + NB2 - 1) ? 1 : 0;
    }
    __syncthreads();
    if (amlast) {
        int tt = threadIdx.x;
        int v1 = (tt < NB1) ? atomicAdd(&bs1[tt], 0) : 0;
        s[tt] = v1;
        __syncthreads();
        for (int off = 1; off < 256; off <<= 1) {
            int u = (tt >= off) ? s[tt - off] : 0;
            __syncthreads();
            s[tt] += u;
            __syncthreads();
        }
        if (tt < NB1) atomicExch(&bs1[tt], s[tt] - v1);
        __syncthreads();
        int v2 = (tt < NB2) ? atomicAdd(&bs2[tt], 0) : 0;
        s[tt] = v2;
        __syncthreads();
        for (int off = 1; off < 256; off <<= 1) {
            int u = (tt >= off) ? s[tt - off] : 0;
            __syncthreads();
            s[tt] += u;
            __syncthreads();
        }
        if (tt < NB2) atomicExch(&bs2[tt], s[tt] - v2);
        __threadfence();
        __syncthreads();
        if (tt == 0) atomicExch(&done[1], 1);
    }
    if (threadIdx.x == 0) {
        while (atomicAdd(&done[1], 0) == 0) __builtin_amdgcn_s_sleep(1);
    }
    __syncthreads();
    __threadfence();
    int base = atomicAdd(&bs[lb], 0);
    s[threadIdx.x] = v;
    __syncthreads();
    for (int off = 1; off < 256; off <<= 1) {
        int u = (threadIdx.x >= off) ? s[threadIdx.x - off] : 0;
        __syncthreads();
        s[threadIdx.x] += u;
        __syncthreads();
    }
    int incl = s[threadIdx.x];
    if (t < n) rp[t] = base + incl - v;
    if (t == n - 1) rp[n] = base + incl;
}

// ---------------------------------------------------------------------------
// fill_both: atomic-free scatter using precomputed ranks
// ---------------------------------------------------------------------------
__global__ __launch_bounds__(256) void fill_both(
    const int* __restrict__ d1, const int* __restrict__ s1,
    const int* __restrict__ et1, const int* __restrict__ ets1,
    const int* __restrict__ rp1, const int* __restrict__ rk1, uint2* __restrict__ ed1,
    const int* __restrict__ d2, const int* __restrict__ s2,
    const int* __restrict__ et2, const int* __restrict__ ets2,
    const int* __restrict__ rp2, const int* __restrict__ rk2, uint2* __restrict__ ed2) {
    int t = blockIdx.x * 256 + threadIdx.x;
    if (t < E1C) {
        int pos = rp1[d1[t]] + rk1[t];
        ed1[pos] = make_uint2((unsigned)s1[t],
                              (unsigned)(et1[t] | (ets1[t] << 16)));
    } else {
        t -= E1C;
        if (t < E2C) {
            int pos = rp2[d2[t]] + rk2[t];
            ed2[pos] = make_uint2((unsigned)s2[t],
                                  (unsigned)(et2[t] | (ets2[t] << 16)));
        }
    }
}

// ---------------------------------------------------------------------------
// Fused aggregation (round-13 best: depth-2 rotation pipeline + DPP)
// ---------------------------------------------------------------------------
__global__ __launch_bounds__(256) void agg_layer1(
    const int* __restrict__ rowptr, const uint2* __restrict__ ED,
    const float* __restrict__ TA, const float* __restrict__ TB,
    const float* __restrict__ QR, const unsigned short* __restrict__ KV,
    const float* __restrict__ Wbeta,
    const float* __restrict__ ln_g, const float* __restrict__ ln_b,
    unsigned short* __restrict__ hout, int n) {
    int wid = (blockIdx.x * blockDim.x + threadIdx.x) >> 6;
    int lane = threadIdx.x & 63;
    if (wid >= n) return;
    int s = lane >> 5, cg = lane & 15;
    int co = ((lane >> 4) & 1) * 64 + 4 * cg;
    int beg = rowptr[wid], end = rowptr[wid + 1];
    float4 q4 = *(const float4*)(QR + (size_t)wid * 256 + co);
    float ax = 0.f, ay = 0.f, az = 0.f, aw = 0.f, suma = 0.f;
    int p = beg + s;
    if (p < end) {
        uint2 d0 = ED[p];
        int pA = p + 2;  bool mA = pA < end;
        uint2 d1 = ED[mA ? pA : beg];
        int pB = p + 4;  bool mB = pB < end;
        uint2 d2 = ED[mB ? pB : beg];
        int sn0 = (int)d0.x, t0 = (int)(d0.y & 0xFFFF), ts0 = (int)(d0.y >> 16);
        float4 ta0 = *(const float4*)(TA + t0 * 128 + co);
        float4 tb0 = *(const float4*)(TB + ts0 * 128 + co);
        const unsigned short* kv0 = KV + (size_t)sn0 * 256;
        ushort4 ku0 = *(const ushort4*)(kv0 + co);
        ushort4 vu0 = *(const ushort4*)(kv0 + 128 + co);
        int sn1 = (int)d1.x, t1 = (int)(d1.y & 0xFFFF), ts1 = (int)(d1.y >> 16);
        float4 ta1 = *(const float4*)(TA + t1 * 128 + co);
        float4 tb1 = *(const float4*)(TB + ts1 * 128 + co);
        const unsigned short* kv1 = KV + (size_t)sn1 * 256;
        ushort4 ku1 = *(const ushort4*)(kv1 + co);
        ushort4 vu1 = *(const ushort4*)(kv1 + 128 + co);
        for (;;) {
            int pC = pB + 2; bool mC = pC < end;
            uint2 d3 = ED[mC ? pC : beg];
            int sn2 = (int)d2.x, t2 = (int)(d2.y & 0xFFFF), ts2 = (int)(d2.y >> 16);
            float4 ta2 = *(const float4*)(TA + t2 * 128 + co);
            float4 tb2 = *(const float4*)(TB + ts2 * 128 + co);
            const unsigned short* kv2 = KV + (size_t)sn2 * 256;
            ushort4 ku2 = *(const ushort4*)(kv2 + co);
            ushort4 vu2 = *(const ushort4*)(kv2 + 128 + co);
            float e0c = ta0.x + tb0.x, e1c = ta0.y + tb0.y;
            float e2c = ta0.z + tb0.z, e3c = ta0.w + tb0.w;
            float pp = q4.x * (b2f(ku0.x) + e0c) + q4.y * (b2f(ku0.y) + e1c)
                     + q4.z * (b2f(ku0.z) + e2c) + q4.w * (b2f(ku0.w) + e3c);
            pp = red16(pp);
            float a = __expf(pp * 0.125f);
            ax += a * (b2f(vu0.x) + e0c); ay += a * (b2f(vu0.y) + e1c);
            az += a * (b2f(vu0.z) + e2c); aw += a * (b2f(vu0.w) + e3c);
            suma += a;
            if (!mA) break;
            ta0 = ta1; tb0 = tb1; ku0 = ku1; vu0 = vu1;
            ta1 = ta2; tb1 = tb2; ku1 = ku2; vu1 = vu2;
            d2 = d3;
            mA = mB; mB = mC; pB = pC;
        }
    }
    ax += __shfl_xor(ax, 32); ay += __shfl_xor(ay, 32);
    az += __shfl_xor(az, 32); aw += __shfl_xor(aw, 32);
    suma += __shfl_xor(suma, 32);
    float inv_s = 1.f / (suma + 1e-16f);
    float ox = ax * inv_s, oy = ay * inv_s, oz = az * inv_s, ow = aw * inv_s;
    float4 r4 = *(const float4*)(QR + (size_t)wid * 256 + 128 + co);
    float4 wo = *(const float4*)(Wbeta + co);
    float4 wr = *(const float4*)(Wbeta + 128 + co);
    float4 wd = *(const float4*)(Wbeta + 256 + co);
    float pb = wo.x * ox + wr.x * r4.x + wd.x * (ox - r4.x)
             + wo.y * oy + wr.y * r4.y + wd.y * (oy - r4.y)
             + wo.z * oz + wr.z * r4.z + wd.z * (oz - r4.z)
             + wo.w * ow + wr.w * r4.w + wd.w * (ow - r4.w);
    pb = red16(pb);
    pb += __shfl_xor(pb, 16);
    float beta = 1.f / (1.f + __expf(-pb));
    float gx = beta * r4.x + (1.f - beta) * ox;
    float gy = beta * r4.y + (1.f - beta) * oy;
    float gz = beta * r4.z + (1.f - beta) * oz;
    float gw = beta * r4.w + (1.f - beta) * ow;
    float sm = gx + gy + gz + gw;
    float sq = gx * gx + gy * gy + gz * gz + gw * gw;
    sm = red16(sm); sm += __shfl_xor(sm, 16);
    sq = red16(sq); sq += __shfl_xor(sq, 16);
    float mu = sm * (1.f / 128.f);
    float var = sq * (1.f / 128.f) - mu * mu;
    float inv = rsqrtf(var + 1e-5f);
    float4 lg = *(const float4*)(ln_g + co);
    float4 lb = *(const float4*)(ln_b + co);
    float yx = (gx - mu) * inv * lg.x + lb.x;
    float yy = (gy - mu) * inv * lg.y + lb.y;
    float yz = (gz - mu) * inv * lg.z + lb.z;
    float yw = (gw - mu) * inv * lg.w + lb.w;
    const float ISQ2 = 0.70710678118654752f;
    yx = 0.5f * yx * (1.f + erff(yx * ISQ2));
    yy = 0.5f * yy * (1.f + erff(yy * ISQ2));
    yz = 0.5f * yz * (1.f + erff(yz * ISQ2));
    yw = 0.5f * yw * (1.f + erff(yw * ISQ2));
    if (s == 0) {
        ushort4 hv;
        hv.x = f2b(yx); hv.y = f2b(yy); hv.z = f2b(yz); hv.w = f2b(yw);
        *(ushort4*)(hout + (size_t)wid * 128 + co) = hv;
    }
}

__global__ __launch_bounds__(256) void agg_layer2(
    const int* __restrict__ rowptr, const uint2* __restrict__ ED,
    const float* __restrict__ TA, const float* __restrict__ TB,
    const float* __restrict__ QR, const unsigned short* __restrict__ KV,
    const float* __restrict__ Wbeta,
    float* __restrict__ o, int n) {
    int wid = (blockIdx.x * blockDim.x + threadIdx.x) >> 6;
    int lane = threadIdx.x & 63;
    if (wid >= n) return;
    int s = lane >> 5, cg = lane & 15;
    int co = ((lane >> 4) & 1) * 64 + 4 * cg;
    int beg = rowptr[wid], end = rowptr[wid + 1];
    float4 q4 = *(const float4*)(QR + (size_t)wid * 192 + co);
    float ax = 0.f, ay = 0.f, az = 0.f, aw = 0.f, suma = 0.f;
    int p = beg + s;
    if (p < end) {
        uint2 d0 = ED[p];
        int pA = p + 2;  bool mA = pA < end;
        uint2 d1 = ED[mA ? pA : beg];
        int pB = p + 4;  bool mB = pB < end;
        uint2 d2 = ED[mB ? pB : beg];
        int sn0 = (int)d0.x, t0 = (int)(d0.y & 0xFFFF), ts0 = (int)(d0.y >> 16);
        float4 ta0 = *(const float4*)(TA + t0 * 128 + co);
        float4 tb0 = *(const float4*)(TB + ts0 * 128 + co);
        const unsigned short* kv0 = KV + (size_t)sn0 * 256;
        ushort4 ku0 = *(const ushort4*)(kv0 + co);
        ushort4 vu0 = *(const ushort4*)(kv0 + 128 + co);
        int sn1 = (int)d1.x, t1 = (int)(d1.y & 0xFFFF), ts1 = (int)(d1.y >> 16);
        float4 ta1 = *(const float4*)(TA + t1 * 128 + co);
        float4 tb1 = *(const float4*)(TB + ts1 * 128 + co);
        const unsigned short* kv1 = KV + (size_t)sn1 * 256;
        ushort4 ku1 = *(const ushort4*)(kv1 + co);
        ushort4 vu1 = *(const ushort4*)(kv1 + 128 + co);
        for (;;) {
            int pC = pB + 2; bool mC = pC < end;
            uint2 d3 = ED[mC ? pC : beg];
            int sn2 = (int)d2.x, t2 = (int)(d2.y & 0xFFFF), ts2 = (int)(d2.y >> 16);
            float4 ta2 = *(const float4*)(TA + t2 * 128 + co);
            float4 tb2 = *(const float4*)(TB + ts2 * 128 + co);
            const unsigned short* kv2 = KV + (size_t)sn2 * 256;
            ushort4 ku2 = *(const ushort4*)(kv2 + co);
            ushort4 vu2 = *(const ushort4*)(kv2 + 128 + co);
            float e0c = ta0.x + tb0.x, e1c = ta0.y + tb0.y;
            float e2c = ta0.z + tb0.z, e3c = ta0.w + tb0.w;
            float pp = q4.x * (b2f(ku0.x) + e0c) + q4.y * (b2f(ku0.y) + e1c)
                     + q4.z * (b2f(ku0.z) + e2c) + q4.w * (b2f(ku0.w) + e3c);
            pp = red16(pp);
            float a = __expf(pp * 0.125f);
            ax += a * (b2f(vu0.x) + e0c); ay += a * (b2f(vu0.y) + e1c);
            az += a * (b2f(vu0.z) + e2c); aw += a * (b2f(vu0.w) + e3c);
            suma += a;
            if (!mA) break;
            ta0 = ta1; tb0 = tb1; ku0 = ku1; vu0 = vu1;
            ta1 = ta2; tb1 = tb2; ku1 = ku2; vu1 = vu2;
            d2 = d3;
            mA = mB; mB = mC; pB = pC;
        }
    }
    ax += __shfl_xor(ax, 32); ay += __shfl_xor(ay, 32);
    az += __shfl_xor(az, 32); aw += __shfl_xor(aw, 32);
    suma += __shfl_xor(suma, 32);
    float inv_s = 1.f / (suma + 1e-16f);
    float ox = ax * inv_s, oy = ay * inv_s, oz = az * inv_s, ow = aw * inv_s;
    ox = 0.5f * (ox + __shfl_xor(ox, 16));
    oy = 0.5f * (oy + __shfl_xor(oy, 16));
    oz = 0.5f * (oz + __shfl_xor(oz, 16));
    ow = 0.5f * (ow + __shfl_xor(ow, 16));
    float4 r4 = *(const float4*)(QR + (size_t)wid * 192 + 128 + 4 * cg);
    float4 wo = *(const float4*)(Wbeta + 4 * cg);
    float4 wr = *(const float4*)(Wbeta + 64 + 4 * cg);
    float4 wd = *(const float4*)(Wbeta + 128 + 4 * cg);
    float pb = wo.x * ox + wr.x * r4.x + wd.x * (ox - r4.x)
             + wo.y * oy + wr.y * r4.y + wd.y * (oy - r4.y)
             + wo.z * oz + wr.z * r4.z + wd.z * (oz - r4.z)
             + wo.w * ow + wr.w * r4.w + wd.w * (ow - r4.w);
    pb = red16(pb);
    float beta = 1.f / (1.f + __expf(-pb));
    float vx = beta * r4.x + (1.f - beta) * ox;
    float vy = beta * r4.y + (1.f - beta) * oy;
    float vz = beta * r4.z + (1.f - beta) * oz;
    float vw = beta * r4.w + (1.f - beta) * ow;
    float m = fmaxf(fmaxf(vx, vy), fmaxf(vz, vw));
    m = red16max(m);
    float se = __expf(vx - m) + __expf(vy - m) + __expf(vz - m) + __expf(vw - m);
    se = red16(se);
    float lse = m + logf(se);
    if (lane < 16)
        *(float4*)(o + (size_t)wid * 64 + 4 * cg) =
            make_float4(vx - lse, vy - lse, vz - lse, vw - lse);
}

extern "C" void kernel_launch(void* const* d_in, const int* in_sizes, int n_in,
                              void* d_out, int out_size, void* d_ws, size_t ws_size,
                              hipStream_t stream) {
    const float* x        = (const float*)d_in[0];
    const int*   ei1_src  = (const int*)d_in[1];
    const int*   ei1_dst  = (const int*)d_in[2];
    const int*   et1      = (const int*)d_in[3];
    const int*   ets1     = (const int*)d_in[4];
    const int*   ei2_src  = (const int*)d_in[5];
    const int*   ei2_dst  = (const int*)d_in[6];
    const int*   et2      = (const int*)d_in[7];
    const int*   ets2     = (const int*)d_in[8];
    const float* edge_W   = (const float*)d_in[9];
    const float* edge_b   = (const float*)d_in[10];
    const float* time_W   = (const float*)d_in[11];
    const float* time_b   = (const float*)d_in[12];
    const float* Wq1      = (const float*)d_in[13];
    const float* bq1      = (const float*)d_in[14];
    const float* Wk1      = (const float*)d_in[15];
    const float* bk1      = (const float*)d_in[16];
    const float* Wv1      = (const float*)d_in[17];
    const float* bv1      = (const float*)d_in[18];
    const float* We1      = (const float*)d_in[19];
    const float* Wskip1   = (const float*)d_in[20];
    const float* bskip1   = (const float*)d_in[21];
    const float* Wbeta1   = (const float*)d_in[22];
    const float* ln_g     = (const float*)d_in[23];
    const float* ln_b     = (const float*)d_in[24];
    const float* Wq2      = (const float*)d_in[25];
    const float* bq2      = (const float*)d_in[26];
    const float* Wk2      = (const float*)d_in[27];
    const float* bk2      = (const float*)d_in[28];
    const float* Wv2      = (const float*)d_in[29];
    const float* bv2      = (const float*)d_in[30];
    const float* We2      = (const float*)d_in[31];
    const float* Wskip2   = (const float*)d_in[32];
    const float* bskip2   = (const float*)d_in[33];
    const float* Wbeta2   = (const float*)d_in[34];

    float* ws = (float*)d_ws;
    unsigned short* xb  = (unsigned short*)(ws + OFF_XB);
    float* qr1          = ws + OFF_QR1;
    unsigned short* kv1 = (unsigned short*)(ws + OFF_KV1);
    unsigned short* h   = (unsigned short*)(ws + OFF_H);
    float* qr2          = ws + OFF_QR2;
    unsigned short* kv2 = (unsigned short*)(ws + OFF_KV2);
    unsigned short* wb1 = (unsigned short*)(ws + OFF_WB1);
    float* bp1          = ws + OFF_BP1;
    unsigned short* wb2 = (unsigned short*)(ws + OFF_WB2);
    float* bp2          = ws + OFF_BP2;
    float* ta1          = ws + OFF_TA1;
    float* tb1          = ws + OFF_TB1;
    float* ta2          = ws + OFF_TA2;
    float* tb2          = ws + OFF_TB2;
    int*   rp1          = (int*)(ws + OFF_RP1);
    int*   cur1         = (int*)(ws + OFF_CUR1);
    uint2* ed1          = (uint2*)(ws + OFF_ED1);
    int*   bs1          = (int*)(ws + OFF_BS1);
    int*   rp2          = (int*)(ws + OFF_RP2);
    int*   cur2         = (int*)(ws + OFF_CUR2);
    uint2* ed2          = (uint2*)(ws + OFF_ED2);
    int*   bs2          = (int*)(ws + OFF_BS2);
    int*   done         = (int*)(ws + OFF_DONE);
    int*   rk1          = (int*)(ws + OFF_RK1);
    int*   rk2          = (int*)(ws + OFF_RK2);

    prep<<<2048, 256, 0, stream>>>(
        x, xb,
        Wk1, Wv1, Wq1, Wskip1, bk1, bv1, bq1, bskip1,
        Wk2, Wv2, Wq2, Wskip2, bk2, bv2, bq2, bskip2,
        wb1, bp1, wb2, bp2,
        edge_W, edge_b, time_W, time_b, We1, We2,
        ta1, tb1, ta2, tb2, cur1, cur2, done);
    mega_l1<<<KV1B + QR1B + CNTB, 256, 0, stream>>>(
        xb, wb1, bp1, kv1, qr1, ei1_dst, ei2_dst, cur1, cur2, rk1, rk2);
    csr_scan<<<NB1 + NB2, 256, 0, stream>>>(cur1, bs1, rp1, cur2, bs2, rp2, done);
    fill_both<<<FILLB, 256, 0, stream>>>(
        ei1_dst, ei1_src, et1, ets1, rp1, rk1, ed1,
        ei2_dst, ei2_src, et2, ets2, rp2, rk2, ed2);
    agg_layer1<<<(N1 + 3) / 4, 256, 0, stream>>>(rp1, ed1,
        ta1, tb1, qr1, kv1, Wbeta1, ln_g, ln_b, h, N1);
    gemm_l2<<<KV2B + QR2B, 256, 0, stream>>>(h, wb2, bp2, kv2, qr2);
    agg_layer2<<<(N2 + 3) / 4, 256, 0, stream>>>(rp2, ed2,
        ta2, tb2, qr2, kv2, Wbeta2, (float*)d_out, N2);
}